// Round 1
// baseline (399.383 us; speedup 1.0000x reference)
//
#include <hip/hip_runtime.h>
#include <hip/hip_bf16.h>
#include <math.h>

// Problem constants (fixed by harness):
// x: (4,16,256,32,64) f32 -> NS=64 samples, CD=256 channels, HW=2048 positions
#define NS 64
#define CD 256
#define HW 2048
#define MD 1024
#define SAMPLE (CD * HW)
#define LN_EPS 1e-5f

typedef __bf16 bf16x8 __attribute__((ext_vector_type(8)));
typedef __bf16 bf16x4 __attribute__((ext_vector_type(4)));
typedef float f32x4 __attribute__((ext_vector_type(4)));

// ---------------- weight prep: f32 -> bf16, transposed ----------------
// w_in (c,m) -> w_in_T [m][c] ; w_out (m,c) -> w_out_T [c][m]
__global__ __launch_bounds__(256) void k_prep(const float* __restrict__ w_in,
                                              const float* __restrict__ w_out,
                                              __bf16* __restrict__ w_in_T,
                                              __bf16* __restrict__ w_out_T) {
  int id = blockIdx.x * 256 + threadIdx.x;  // 0..262143
  int mm = id >> 8, cc = id & 255;
  w_in_T[id] = (__bf16)w_in[cc * MD + mm];
  int cc2 = id >> 10, mm2 = id & 1023;
  w_out_T[id] = (__bf16)w_out[mm2 * CD + cc2];
}

// ---------------- LN stats, stage 1: partial sums ----------------
// grid = 64 samples * 8 slices; 256 threads; each block reduces 65536 elems
__global__ __launch_bounds__(256) void k_stats1(const float* __restrict__ x,
                                                double* __restrict__ partial) {
  int s = blockIdx.x >> 3, sl = blockIdx.x & 7;
  const float4* p = (const float4*)(x + (size_t)s * SAMPLE + (size_t)sl * 65536);
  double sum = 0.0, ssq = 0.0;
  for (int i = 0; i < 64; ++i) {
    float4 v = p[i * 256 + threadIdx.x];
    sum += (double)v.x + (double)v.y + (double)v.z + (double)v.w;
    ssq += (double)v.x * v.x + (double)v.y * v.y + (double)v.z * v.z + (double)v.w * v.w;
  }
  for (int off = 32; off; off >>= 1) {
    sum += __shfl_down(sum, off);
    ssq += __shfl_down(ssq, off);
  }
  __shared__ double red[4][2];
  int wv = threadIdx.x >> 6, ln = threadIdx.x & 63;
  if (ln == 0) { red[wv][0] = sum; red[wv][1] = ssq; }
  __syncthreads();
  if (threadIdx.x == 0) {
    for (int i = 1; i < 4; ++i) { sum += red[i][0]; ssq += red[i][1]; }
    partial[blockIdx.x * 2] = sum;
    partial[blockIdx.x * 2 + 1] = ssq;
  }
}

// ---------------- LN stats, stage 2: mean/rstd per sample ----------------
__global__ void k_stats2(const double* __restrict__ partial, float* __restrict__ stats) {
  int s = threadIdx.x;  // 64 threads
  double sum = 0.0, ssq = 0.0;
  for (int i = 0; i < 8; ++i) {
    sum += partial[(s * 8 + i) * 2];
    ssq += partial[(s * 8 + i) * 2 + 1];
  }
  double mean = sum / (double)SAMPLE;
  double var = ssq / (double)SAMPLE - mean * mean;
  stats[s * 2] = (float)mean;
  stats[s * 2 + 1] = (float)(1.0 / sqrt(var + (double)LN_EPS));
}

// ---------------- fused LN + MLP + layer-scale + residual ----------------
// Tile: 128 positions x full pipeline. 8 waves (512 thr). LDS:
//   Ysh  [128][264] bf16  normalized input, [p][c] (K-contig for MFMA B/A)
//   Wsh1 [64][264]  bf16  w_in_T chunk rows m0..m0+63           (GEMM1 A)
//   Wsh2 [256][72]  bf16  w_out_T cols m0..m0+63, all 256 c     (GEMM2 B)
//   Tsh  [128][72]  bf16  GELU(T) chunk, [p][m]                 (GEMM2 A)
#define YS 264
#define TS 72
#define LDS_ELEMS (128 * YS + 64 * YS + 256 * TS + 128 * TS)  // 78336 bf16 = 156672 B

__global__ __launch_bounds__(512, 2) void k_fused(
    const float* __restrict__ x, const float* __restrict__ ln_w, const float* __restrict__ ln_b,
    const float* __restrict__ b_in, const float* __restrict__ b_out, const float* __restrict__ gamma,
    const __bf16* __restrict__ w_in_T, const __bf16* __restrict__ w_out_T,
    const float* __restrict__ stats, float* __restrict__ out) {
  extern __shared__ __bf16 smem[];
  __bf16* Ysh = smem;                    // [128][YS]
  __bf16* Wsh1 = Ysh + 128 * YS;         // [64][YS]
  __bf16* Wsh2 = Wsh1 + 64 * YS;         // [256][TS]
  __bf16* Tsh = Wsh2 + 256 * TS;         // [128][TS]

  const int tid = threadIdx.x;
  const int s = blockIdx.x >> 4;
  const int p0 = (blockIdx.x & 15) * 128;
  const float mu = stats[s * 2], rstd = stats[s * 2 + 1];
  const float a_ln = rstd, c_ln = -mu * rstd;
  const size_t xbase = (size_t)s * SAMPLE;

  // ---- stage Ysh: normalize + affine, transpose (c,p)->(p,c), cvt bf16 ----
  #pragma unroll
  for (int it = 0; it < 4; ++it) {
    int bid = it * 512 + tid;  // 2048 4x4 micro-blocks
    int c0 = (bid >> 5) * 4, pp = (bid & 31) * 4;
    float4 xv[4], lw[4], lb[4];
    #pragma unroll
    for (int i = 0; i < 4; ++i) {
      size_t off = (size_t)(c0 + i) * HW + p0 + pp;
      xv[i] = *(const float4*)(x + xbase + off);
      lw[i] = *(const float4*)(ln_w + off);
      lb[i] = *(const float4*)(ln_b + off);
    }
    #pragma unroll
    for (int j = 0; j < 4; ++j) {
      bf16x4 v;
      #pragma unroll
      for (int i = 0; i < 4; ++i) {
        float xx = ((const float*)&xv[i])[j];
        float y = fmaf(xx, a_ln, c_ln);
        v[i] = (__bf16)fmaf(y, ((const float*)&lw[i])[j], ((const float*)&lb[i])[j]);
      }
      *(bf16x4*)&Ysh[(pp + j) * YS + c0] = v;
    }
  }

  const int lane = tid & 63;
  const int l15 = lane & 15, l4 = lane >> 4;
  const int w = tid >> 6;
  const int wq = w & 3, wp = w >> 2;  // GEMM1: m-block 16*wq, p-block 64*wp
  const int wr = w >> 2, wc = w & 3;  // GEMM2: p-block 64*wr, c-block 64*wc

  f32x4 acc2[4][4] = {};  // persistent output accumulator 64p x 64c per wave

  __syncthreads();  // Ysh ready

  for (int ch = 0; ch < 16; ++ch) {
    const int m0 = ch * 64;
    if (ch) __syncthreads();  // protect Wsh1/Wsh2/Tsh overwrite vs prev reads

    // stage Wsh1: rows m0..m0+63 of w_in_T (64 x 256 bf16)
    #pragma unroll
    for (int it = 0; it < 4; ++it) {
      int idx = it * 512 + tid;
      int mm = idx >> 5, cq = idx & 31;
      *(bf16x8*)&Wsh1[mm * YS + cq * 8] =
          *(const bf16x8*)&w_in_T[(size_t)(m0 + mm) * CD + cq * 8];
    }
    // stage Wsh2: all 256 c-rows, cols m0..m0+63 of w_out_T (256 x 64 bf16)
    #pragma unroll
    for (int it = 0; it < 4; ++it) {
      int idx = it * 512 + tid;
      int cc = idx >> 3, q = idx & 7;
      *(bf16x8*)&Wsh2[cc * TS + q * 8] =
          *(const bf16x8*)&w_out_T[(size_t)cc * MD + m0 + q * 8];
    }
    __syncthreads();

    // GEMM1 (swapped): D1[m][p] = w_in_T_chunk (64x256) @ Y^T (256x128)
    // wave slice: rows m 16*wq..+15 (1 frag), cols p 64*wp..+63 (4 frags)
    f32x4 acc1[4] = {};
    #pragma unroll
    for (int kk = 0; kk < 8; ++kk) {
      bf16x8 a = *(const bf16x8*)&Wsh1[(16 * wq + l15) * YS + kk * 32 + l4 * 8];
      #pragma unroll
      for (int pi = 0; pi < 4; ++pi) {
        bf16x8 b = *(const bf16x8*)&Ysh[(64 * wp + pi * 16 + l15) * YS + kk * 32 + l4 * 8];
        acc1[pi] = __builtin_amdgcn_mfma_f32_16x16x32_bf16(a, b, acc1[pi], 0, 0, 0);
      }
    }
    // epilogue: +b_in, exact GELU, pack 4 consecutive m -> Tsh[p][m]
    float4 binv = *(const float4*)&b_in[m0 + 16 * wq + 4 * l4];
    #pragma unroll
    for (int pi = 0; pi < 4; ++pi) {
      int p = 64 * wp + pi * 16 + l15;
      bf16x4 tv;
      #pragma unroll
      for (int r = 0; r < 4; ++r) {
        float t = acc1[pi][r] + ((const float*)&binv)[r];
        float g = 0.5f * t * (1.0f + erff(t * 0.70710678118654752f));
        tv[r] = (__bf16)g;
      }
      *(bf16x4*)&Tsh[p * TS + 16 * wq + 4 * l4] = tv;
    }
    __syncthreads();

    // GEMM2: acc2 += T (128 x 64) @ w_out_chunk (64 x 256)
    // wave slice: rows p 64*wr..+63 (4 frags), cols c 64*wc..+63 (4 frags)
    #pragma unroll
    for (int kk = 0; kk < 2; ++kk) {
      bf16x8 a2[4], b2[4];
      #pragma unroll
      for (int mi = 0; mi < 4; ++mi)
        a2[mi] = *(const bf16x8*)&Tsh[(64 * wr + mi * 16 + l15) * TS + kk * 32 + l4 * 8];
      #pragma unroll
      for (int ni = 0; ni < 4; ++ni)
        b2[ni] = *(const bf16x8*)&Wsh2[(64 * wc + ni * 16 + l15) * TS + kk * 32 + l4 * 8];
      #pragma unroll
      for (int mi = 0; mi < 4; ++mi)
        #pragma unroll
        for (int ni = 0; ni < 4; ++ni)
          acc2[mi][ni] = __builtin_amdgcn_mfma_f32_16x16x32_bf16(a2[mi], b2[ni], acc2[mi][ni], 0, 0, 0);
    }
  }

  // ---- epilogue: out = x + gamma_c * (v + b_out_c) ----
  #pragma unroll
  for (int ni = 0; ni < 4; ++ni) {
    int cc = 64 * wc + 16 * ni + l15;
    float g = gamma[cc], bo = b_out[cc];
    #pragma unroll
    for (int mi = 0; mi < 4; ++mi) {
      int p = p0 + 64 * wr + 16 * mi + 4 * l4;
      size_t off = xbase + (size_t)cc * HW + p;
      float4 xv = *(const float4*)(x + off);
      float4 o;
      #pragma unroll
      for (int r = 0; r < 4; ++r)
        ((float*)&o)[r] = ((const float*)&xv)[r] + g * (acc2[mi][ni][r] + bo);
      *(float4*)(out + off) = o;
    }
  }
}

extern "C" void kernel_launch(void* const* d_in, const int* in_sizes, int n_in,
                              void* d_out, int out_size, void* d_ws, size_t ws_size,
                              hipStream_t stream) {
  const float* x = (const float*)d_in[0];
  const float* ln_w = (const float*)d_in[1];
  const float* ln_b = (const float*)d_in[2];
  const float* w_in = (const float*)d_in[3];
  const float* b_in = (const float*)d_in[4];
  const float* w_out = (const float*)d_in[5];
  const float* b_out = (const float*)d_in[6];
  const float* gamma = (const float*)d_in[7];
  float* out = (float*)d_out;

  char* ws = (char*)d_ws;
  __bf16* w_in_T = (__bf16*)ws;                     // 262144 bf16 = 512 KB
  __bf16* w_out_T = (__bf16*)(ws + 524288);         // 262144 bf16 = 512 KB
  double* partial = (double*)(ws + 1048576);        // 512*2 doubles = 8 KB
  float* stats = (float*)(ws + 1048576 + 8192);     // 64*2 floats

  k_prep<<<1024, 256, 0, stream>>>(w_in, w_out, w_in_T, w_out_T);
  k_stats1<<<512, 256, 0, stream>>>(x, partial);
  k_stats2<<<1, 64, 0, stream>>>(partial, stats);

  const int lds_bytes = LDS_ELEMS * 2;  // 156672
  hipFuncSetAttribute((const void*)k_fused, hipFuncAttributeMaxDynamicSharedMemorySize,
                      lds_bytes);
  k_fused<<<1024, 512, lds_bytes, stream>>>(x, ln_w, ln_b, b_in, b_out, gamma,
                                            w_in_T, w_out_T, stats, out);
}